// Round 13
// baseline (127.757 us; speedup 1.0000x reference)
//
#include <hip/hip_runtime.h>

typedef float v2f __attribute__((ext_vector_type(2)));
typedef float v4f __attribute__((ext_vector_type(4)));

#define HW      1024   // H*W = BN channel count (spatial positions)
#define NROWS   4096   // B*C = reduction size per channel
#define NLAYERS 30

// ---------------------------------------------------------------------------
// Packed-f32 VOP3P ops (asm outputs also pin results into registers).
// ---------------------------------------------------------------------------
static __device__ __forceinline__ v2f pk_fma(v2f a, v2f b, v2f c) {
    v2f d; asm("v_pk_fma_f32 %0, %1, %2, %3" : "=v"(d) : "v"(a), "v"(b), "v"(c));
    return d;
}
static __device__ __forceinline__ v2f pk_add(v2f a, v2f b) {
    v2f d; asm("v_pk_add_f32 %0, %1, %2" : "=v"(d) : "v"(a), "v"(b));
    return d;
}

// ---------------------------------------------------------------------------
// DPP-based wave64 sum: pure VALU, lane 63 = wave total.
// ---------------------------------------------------------------------------
template <int CTRL, int RMASK>
__device__ __forceinline__ float dpp_add(float x) {
    int t = __builtin_amdgcn_update_dpp(0, __builtin_bit_cast(int, x),
                                        CTRL, RMASK, 0xf, true);
    return x + __builtin_bit_cast(float, t);
}
__device__ __forceinline__ float wave_sum64(float x) {
    x = dpp_add<0x111, 0xf>(x);   // row_shr:1
    x = dpp_add<0x112, 0xf>(x);   // row_shr:2
    x = dpp_add<0x114, 0xf>(x);   // row_shr:4
    x = dpp_add<0x118, 0xf>(x);   // row_shr:8
    x = dpp_add<0x142, 0xa>(x);   // row_bcast15 -> rows 1,3
    x = dpp_add<0x143, 0xc>(x);   // row_bcast31 -> rows 2,3
    return x;                     // lane 63 = wave total
}
__device__ __forceinline__ float bcast63(float x) {
    return __builtin_bit_cast(float,
        __builtin_amdgcn_readlane(__builtin_bit_cast(int, x), 63));
}

// ---------------------------------------------------------------------------
// Single direct kernel: no workspace, no transposes, no LDS, no barriers.
// ONE wave per channel p (XCD-swizzled so the 16 channels sharing each 64B
// line of x sit on the same XCD -> L2/L3 serves 15/16 line-touches).
// Lane owns elements e = 4*lane + 256*j + i (j=0..15, i=0..3); scattered
// one-time gather/scatter at stride 4KB (~7 us each phase chip-wide),
// paid ONCE — unlike R0's per-layer barriers or R7-R12's 32MB ws sandwich.
// Math is verbatim R12 (z-only recurrence, all-register, absmax-verified):
//   z_{k+1} = om*z_k + dm*x1 + med3(gd*z_k + bd, 0, 6dt),
//     om = 1-dt, dm = m_{k+1} - om*m_k, gd = dt*g, bd = dt*b
//   out = same step with m_30 := 1  (out = y_30 + x1).
// Regs: x1 16 v4f (64) + z 32 v2f (64) + temps ~= 170 < 256 @ (64,1).
// ---------------------------------------------------------------------------
__global__ __launch_bounds__(64, 1) void ode_direct(
    const float* __restrict__ x, const float* __restrict__ delta_t,
    const float* __restrict__ matrices, const float* __restrict__ gamma,
    const float* __restrict__ beta, float* __restrict__ out) {

    const int bid  = blockIdx.x;
    const int p    = ((bid & 7) << 7) | (bid >> 3);   // XCD-contiguous channel
    const int lane = threadIdx.x;                     // 0..63
    const int c0   = 4 * lane;                        // matrix quad base

    const float gp = gamma[p];
    const float bp = beta[p];

    // Per-lane base: element e -> x[e*HW + p]; e = 4*lane + 256*j + i.
    const float* xp = x + (size_t)(4 * lane) * HW + p;
    float*       op = out + (size_t)(4 * lane) * HW + p;

    v4f xr[16];                            // x1, permanently in registers
    v2f z[32];
    v2f s0 = {0.f, 0.f}, s1 = {0.f, 0.f}, q0 = {0.f, 0.f}, q1 = {0.f, 0.f};

    // One-time scattered gather (64 scalar loads) + layer 0:
    // z0 = (m0+1)*x1, + stats.
    {
        const v4f m4 = *(const v4f*)(matrices + c0);
        const v2f mA = {m4.x, m4.y}, mB = {m4.z, m4.w};
#pragma unroll
        for (int j = 0; j < 16; ++j) {
            const size_t base = (size_t)(256 * j) * HW;   // 256j rows down
            v4f v;
            v.x = xp[base];
            v.y = xp[base + HW];
            v.z = xp[base + 2 * (size_t)HW];
            v.w = xp[base + 3 * (size_t)HW];
            xr[j] = v;
            const v2f xA = {v.x, v.y}, xB = {v.z, v.w};
            z[2 * j]     = pk_fma(mA, xA, xA);     // m0*x1 + x1
            z[2 * j + 1] = pk_fma(mB, xB, xB);
            s0 = pk_add(s0, z[2 * j]);
            q0 = pk_fma(z[2 * j], z[2 * j], q0);
            s1 = pk_add(s1, z[2 * j + 1]);
            q1 = pk_fma(z[2 * j + 1], z[2 * j + 1], q1);
        }
    }

    v4f   mqc = *(const v4f*)(matrices + c0);          // m_k   (k=0)
    v4f   mqn = *(const v4f*)(matrices + 256 + c0);    // m_{k+1}
    float dtc = delta_t[0];
    float dtn = delta_t[1];

    for (int k = 0; k < NLAYERS - 1; ++k) {
        // Pin x1 registers: forbids remat-as-reload inside the loop.
        asm volatile("" : "+v"(xr[0]), "+v"(xr[1]), "+v"(xr[2]), "+v"(xr[3]));
        asm volatile("" : "+v"(xr[4]), "+v"(xr[5]), "+v"(xr[6]), "+v"(xr[7]));
        asm volatile("" : "+v"(xr[8]), "+v"(xr[9]), "+v"(xr[10]), "+v"(xr[11]));
        asm volatile("" : "+v"(xr[12]), "+v"(xr[13]), "+v"(xr[14]), "+v"(xr[15]));

        // Prefetch m_{k+2}/dt_{k+2}: ~2 layers of cover, no barrier to
        // drain vmcnt -> latency fully hidden.
        const int k2 = (k + 2 < NLAYERS) ? k + 2 : NLAYERS - 1;
        const v4f   mq2   = *(const v4f*)(matrices + k2 * 256 + c0);
        const float dt_nn = delta_t[k2];

        // In-wave stats of z_k.
        const v2f sv = pk_add(s0, s1);
        const v2f qv = pk_add(q0, q1);
        const float S = bcast63(wave_sum64(sv.x + sv.y));
        const float Q = bcast63(wave_sum64(qv.x + qv.y));

        const float dtk  = __builtin_amdgcn_fmed3f(dtc, 0.0f, 6.0f);
        const float mean = S * (1.0f / 4096.0f);
        const float var  = fmaf(-mean, mean, Q * (1.0f / 4096.0f));
        const float rstd = rsqrtf(var + 1e-5f);
        const float g    = gp * rstd;                  // gamma folded
        const float b    = fmaf(-mean, g, bp);         // mean folded
        const float om   = 1.0f - dtk;
        const float gd   = g * dtk;                    // dt folded into clamp
        const float bd   = b * dtk;
        const float hi   = 6.0f * dtk;
        const v2f gd2 = {gd, gd}, bd2 = {bd, bd};
        const v2f om2 = {om, om};
        const v2f omn = {-om, -om};
        const v2f mcA = {mqc.x, mqc.y}, mcB = {mqc.z, mqc.w};
        const v2f mnA = {mqn.x, mqn.y}, mnB = {mqn.z, mqn.w};
        const v2f dmA = pk_fma(omn, mcA, mnA);         // m_{k+1} - om*m_k
        const v2f dmB = pk_fma(omn, mcB, mnB);

        s0 = (v2f){0.f, 0.f}; s1 = (v2f){0.f, 0.f};
        q0 = (v2f){0.f, 0.f}; q1 = (v2f){0.f, 0.f};

        // Fused pass: z' = om*z + dm*x1 + med3(gd*z+bd, 0, hi), + stats.
#pragma unroll
        for (int j = 0; j < 16; ++j) {
            const v2f xA = {xr[j].x, xr[j].y}, xB = {xr[j].z, xr[j].w};
            {
                const int e = 2 * j;
                v2f a = pk_fma(z[e], gd2, bd2);
                a.x = __builtin_amdgcn_fmed3f(a.x, 0.0f, hi);
                a.y = __builtin_amdgcn_fmed3f(a.y, 0.0f, hi);
                v2f u = pk_fma(dmA, xA, a);
                z[e] = pk_fma(om2, z[e], u);
                s0 = pk_add(s0, z[e]);
                q0 = pk_fma(z[e], z[e], q0);
            }
            {
                const int e = 2 * j + 1;
                v2f a = pk_fma(z[e], gd2, bd2);
                a.x = __builtin_amdgcn_fmed3f(a.x, 0.0f, hi);
                a.y = __builtin_amdgcn_fmed3f(a.y, 0.0f, hi);
                v2f u = pk_fma(dmB, xB, a);
                z[e] = pk_fma(om2, z[e], u);
                s1 = pk_add(s1, z[e]);
                q1 = pk_fma(z[e], z[e], q1);
            }
        }

        mqc = mqn; mqn = mq2; dtc = dtn; dtn = dt_nn;
    }

    // Final layer (k = 29): same step with m_30 := 1 -> out = y_30 + x1,
    // one-time scattered scatter (64 scalar stores, fire-and-forget).
    {
        const v2f sv = pk_add(s0, s1);
        const v2f qv = pk_add(q0, q1);
        const float S = bcast63(wave_sum64(sv.x + sv.y));
        const float Q = bcast63(wave_sum64(qv.x + qv.y));

        const float dtk  = __builtin_amdgcn_fmed3f(dtc, 0.0f, 6.0f);
        const float mean = S * (1.0f / 4096.0f);
        const float var  = fmaf(-mean, mean, Q * (1.0f / 4096.0f));
        const float rstd = rsqrtf(var + 1e-5f);
        const float g    = gp * rstd;
        const float b    = fmaf(-mean, g, bp);
        const float om   = 1.0f - dtk;
        const float gd   = g * dtk;
        const float bd   = b * dtk;
        const float hi   = 6.0f * dtk;
        const v2f gd2 = {gd, gd}, bd2 = {bd, bd};
        const v2f om2 = {om, om};
        const v2f omn = {-om, -om};
        const v2f one2 = {1.0f, 1.0f};
        const v2f mcA = {mqc.x, mqc.y}, mcB = {mqc.z, mqc.w};
        const v2f dmA = pk_fma(omn, mcA, one2);   // 1 - om*m_29
        const v2f dmB = pk_fma(omn, mcB, one2);

#pragma unroll
        for (int j = 0; j < 16; ++j) {
            const v2f xA = {xr[j].x, xr[j].y}, xB = {xr[j].z, xr[j].w};
            v2f o0, o1;
            {
                v2f a = pk_fma(z[2 * j], gd2, bd2);
                a.x = __builtin_amdgcn_fmed3f(a.x, 0.0f, hi);
                a.y = __builtin_amdgcn_fmed3f(a.y, 0.0f, hi);
                v2f u = pk_fma(dmA, xA, a);
                o0 = pk_fma(om2, z[2 * j], u);
            }
            {
                v2f a = pk_fma(z[2 * j + 1], gd2, bd2);
                a.x = __builtin_amdgcn_fmed3f(a.x, 0.0f, hi);
                a.y = __builtin_amdgcn_fmed3f(a.y, 0.0f, hi);
                v2f u = pk_fma(dmB, xB, a);
                o1 = pk_fma(om2, z[2 * j + 1], u);
            }
            const size_t base = (size_t)(256 * j) * HW;
            op[base]                 = o0.x;
            op[base + HW]            = o0.y;
            op[base + 2 * (size_t)HW] = o1.x;
            op[base + 3 * (size_t)HW] = o1.y;
        }
    }
}

extern "C" void kernel_launch(void* const* d_in, const int* in_sizes, int n_in,
                              void* d_out, int out_size, void* d_ws, size_t ws_size,
                              hipStream_t stream) {
    const float* x        = (const float*)d_in[0];   // [16,256,32,32]
    const float* delta_t  = (const float*)d_in[1];   // [30,1]
    const float* matrices = (const float*)d_in[2];   // [30,1,1,16,16]
    const float* gamma    = (const float*)d_in[3];   // [1024]
    const float* beta     = (const float*)d_in[4];   // [1024]
    float* out = (float*)d_out;

    ode_direct<<<dim3(HW), dim3(64), 0, stream>>>(x, delta_t, matrices, gamma, beta, out);
}